// Round 5
// baseline (310.316 us; speedup 1.0000x reference)
//
#include <hip/hip_runtime.h>

// InnerShiftTriple: bz=4, c=512 (c2=256), h=w=64 (hw=4096), fp32 in/out, int32 mask.
// out = concat([former, latter, shifted]); shifted[i] = former[argmax_j sim(i,j)]
// for masked i over non-masked keys j, cosine sim of "latter" features.
// Argmax invariant to query normalization -> only keys normalized.
//
// Pass1: queries wave-uniform -> SGPR broadcast (s_load_dwordx16); keys stream
// as one float2/thread/channel. R4 lesson: remainder split along q failed --
// an 8q item streams the SAME 512KB key slice as a 32q item (key cost is
// per-slice), latency-bound at low occupancy: 58us for quarter work. This
// round: (a) item = 16q x 512k (~2100 items, FMA still 86% of issue), and
// (b) DYNAMIC work stealing via global atomic ticket (zeroed in prep) ->
// no ceil-quantization, tail = one small-item wall (~10us) instead of a
// near-full round. Register budget: acc[2][16]=32 floats, combined V+A ~80
// <= 128-reg cap of launch_bounds(256,4) -- NOT raising residency (R3 spill).
// Per-query fmaf chains unchanged -> bit-identical argmax.

#define HW 4096
#define C2 256
#define BZd 4
#define TQ 16         // queries per work item (SGPR-broadcast)
#define NK 2          // keys per thread (one float2)
#define BT 256        // pass1 block = 4 waves; block covers BT*NK = 512 keys
#define SLK 512       // keys per slice
#define NSL_MAX 8     // up to 8 slices of 512 keys
#define QT16_MAX 256  // HW/TQ
#define P1_GRID 1024  // exactly the resident capacity at 4 blocks/CU

__device__ __forceinline__ unsigned ordf(float f) {
  unsigned u = __float_as_uint(f);
  return (u & 0x80000000u) ? ~u : (u | 0x80000000u);
}

__device__ __forceinline__ unsigned long long shfl_down_u64(unsigned long long v, int off) {
  unsigned lo = (unsigned)v, hi = (unsigned)(v >> 32);
  lo = __shfl_down(lo, off, 64);
  hi = __shfl_down(hi, off, 64);
  return ((unsigned long long)hi << 32) | lo;
}

// --- K1: fused inv-norm (blocks 0..63) + mask compaction (blocks 64..67) -----
__global__ void prep_kernel(const float* __restrict__ in, const int* __restrict__ mask,
                            float* __restrict__ inv, int* __restrict__ qcnt,
                            int* __restrict__ kcnt, int* __restrict__ qlist,
                            int* __restrict__ klist, int* __restrict__ srcmap,
                            unsigned* __restrict__ wcnt) {
  __shared__ int s[256];
  int bid = blockIdx.x, t = threadIdx.x;
  if (bid < 64) {
    int idx = bid * 256 + t;                  // [0, 16384)
    int b = idx >> 12, j = idx & (HW - 1);
    const float* p = in + ((size_t)b * 512 + C2) * HW + j;
    float ss = 0.f;
#pragma unroll 8
    for (int c = 0; c < C2; ++c) { float v = p[(size_t)c * HW]; ss = fmaf(v, v, ss); }
    inv[idx] = 1.0f / (sqrtf(ss) + 1e-8f);
  } else {
    int b = bid - 64;
    if (b == 0 && t == 0) wcnt[0] = 0;        // reset pass1 work-steal ticket
    const int* m = mask + b * HW;
    int base = t * 16;
    int fl = 0, cq = 0;
#pragma unroll
    for (int i = 0; i < 16; ++i) { int f = (m[base + i] >= 1); fl |= f << i; cq += f; }
    s[t] = cq; __syncthreads();
    for (int off = 1; off < 256; off <<= 1) {
      int v = (t >= off) ? s[t - off] : 0;
      __syncthreads(); s[t] += v; __syncthreads();
    }
    int total = s[255];
    int qp = s[t] - cq;
    int kp = base - qp;
    for (int i = 0; i < 16; ++i) {
      int j = base + i;
      if ((fl >> i) & 1) qlist[b * HW + qp++] = j;
      else               klist[b * HW + kp++] = j;
      srcmap[b * HW + j] = -1;
    }
    if (t == 0) { qcnt[b] = total; kcnt[b] = HW - total; }
  }
}

// --- K2: pack normalized keys + un-normalized queries.
// kpack[(b*C2+c)*HW + kk] holds normalized key at packed index kk (0 beyond kcnt).
// qpack[(b*C2+c)*HW + jj] holds query at packed position jj (0 beyond qcnt).
__global__ void pack_kernel(const float* __restrict__ in, const float* __restrict__ inv,
                            const int* __restrict__ qcnt, const int* __restrict__ kcnt,
                            const int* __restrict__ qlist, const int* __restrict__ klist,
                            float* __restrict__ kpack, float* __restrict__ qpack) {
  int t = threadIdx.x;
  int x = blockIdx.x;           // [0,8): 0..3 key chunks (1024 each), 4..7 query chunks
  int c = blockIdx.y, b = blockIdx.z;
  const float* lat = in + ((size_t)b * 512 + C2 + c) * HW;
  if (x < 4) {
    int kc = kcnt[b];
    const float* dn = inv + b * HW;
    int base = (x << 10) + (t << 2);
    float v[4];
#pragma unroll
    for (int r = 0; r < 4; ++r) {
      int kk = base + r;
      float val = 0.f;
      if (kk < kc) { int j = klist[b * HW + kk]; val = lat[j] * dn[j]; }
      v[r] = val;
    }
    float* dst = kpack + ((size_t)(b * C2 + c)) * HW + base;
    *(float4*)dst = make_float4(v[0], v[1], v[2], v[3]);
  } else {
    int qc = x - 4, nq = qcnt[b];
    float* dst = qpack + ((size_t)(b * C2 + c)) * HW;
#pragma unroll
    for (int r = 0; r < 4; ++r) {
      int jj = (qc << 10) + (r << 8) + t;
      float val = 0.f;
      if (jj < nq) val = lat[qlist[b * HW + jj]];
      dst[jj] = val;
    }
  }
}

// --- K3 helpers --------------------------------------------------------------
__device__ __forceinline__ void decode_id(unsigned idx,
    int nt0, int nt1, int nt2,
    int q0, int q1, int q2, int q3,
    int k0c, int k1c, int k2c, int k3c,
    int& b, int& sl, int& qtile, int& kc) {
  int qtn;
  b = 0; qtn = q0; kc = k0c;
  if (idx >= (unsigned)nt0) {
    idx -= nt0; b = 1; qtn = q1; kc = k1c;
    if (idx >= (unsigned)nt1) {
      idx -= nt1; b = 2; qtn = q2; kc = k2c;
      if (idx >= (unsigned)nt2) { idx -= nt2; b = 3; qtn = q3; kc = k3c; }
    }
  }
  sl = (int)(idx / (unsigned)qtn);
  qtile = (int)(idx - (unsigned)sl * (unsigned)qtn);
}

// One work item: TQ=16 queries x one 512-key slice, full C2 dot products.
// Per-query fmaf chain identical to previous rounds -> bit-exact argmax.
__device__ __forceinline__ void run_item(
    const float* __restrict__ qpack, const float* __restrict__ kpack,
    unsigned long long* __restrict__ partials,
    unsigned long long (*red)[TQ],
    int b, int sl, int qtile, int kc,
    int t, int lane, int wid) {
  int qstart = qtile << 4;
  int kbase = (sl << 9) + (t << 1);   // this thread's 2 keys

  // wave-uniform query base -> scalar loads (SGPR broadcast operands)
  const float* qb = qpack + ((size_t)b * C2) * HW + qstart;
  const float* kcol = kpack + ((size_t)b * C2) * HW + kbase;

  float acc[NK][TQ];
#pragma unroll
  for (int r = 0; r < NK; ++r)
#pragma unroll
    for (int q = 0; q < TQ; ++q) acc[r][q] = 0.f;

  // rotating depth-2 prefetch of the key float2 (stride HW floats per c)
  float2 k0 = *(const float2*)(kcol);
  float2 k1 = *(const float2*)(kcol + HW);
#pragma unroll 2
  for (int c = 0; c < C2; ++c) {
    float2 kq = k0;
    k0 = k1;
    int cp = c + 2; if (cp > C2 - 1) cp = C2 - 1;
    k1 = *(const float2*)(kcol + (size_t)cp * HW);
    float kv[NK] = {kq.x, kq.y};
    const float* qc_ = qb + (size_t)c * HW;   // uniform address
#pragma unroll
    for (int i = 0; i < TQ; ++i) {
      float qv = qc_[i];                       // s_load -> SGPR
#pragma unroll
      for (int r = 0; r < NK; ++r)
        acc[r][i] = fmaf(kv[r], qv, acc[r][i]);
    }
  }

  // per-q reduction: wave shfl, then cross-wave via LDS
#pragma unroll
  for (int q = 0; q < TQ; ++q) {
    unsigned long long v = 0ull;
#pragma unroll
    for (int r = 0; r < NK; ++r) {
      int kk = kbase + r;
      if (kk < kc) {
        unsigned long long pk =
            ((unsigned long long)ordf(acc[r][q]) << 32) | (unsigned)(0xFFFFFFFFu - (unsigned)kk);
        if (pk > v) v = pk;
      }
    }
#pragma unroll
    for (int off = 32; off >= 1; off >>= 1) {
      unsigned long long o = shfl_down_u64(v, off);
      if (o > v) v = o;
    }
    if (lane == 0) red[wid][q] = v;
  }
  __syncthreads();
  if (t < TQ) {
    unsigned long long v = red[0][t];
#pragma unroll
    for (int ww = 1; ww < 4; ++ww) if (red[ww][t] > v) v = red[ww][t];
    partials[(((size_t)b * NSL_MAX + sl) * QT16_MAX + qtile) * TQ + t] = v;
  }
  __syncthreads();
}

// --- K3: fused GEMM + per-slice argmax, dynamic work stealing ----------------
// Items enumerated qtile-fastest within a slice (concurrent blocks share the
// key-slice stream in L2). Global atomic ticket -> zero static quantization;
// tail = one in-flight item per slot (~10us at 16q granularity).
__global__ __launch_bounds__(BT, 4) void argmax_pass1(
    const float* __restrict__ qpack, const float* __restrict__ kpack,
    const int* __restrict__ qcnt, const int* __restrict__ kcnt,
    unsigned long long* __restrict__ partials, unsigned* __restrict__ wcnt) {
  // per-batch work-item counts (uniform -> scalar)
  int k0c = kcnt[0], k1c = kcnt[1], k2c = kcnt[2], k3c = kcnt[3];
  int s0 = (k0c + SLK - 1) >> 9, s1 = (k1c + SLK - 1) >> 9;
  int s2 = (k2c + SLK - 1) >> 9, s3 = (k3c + SLK - 1) >> 9;
  int q0 = (qcnt[0] + TQ - 1) >> 4, q1 = (qcnt[1] + TQ - 1) >> 4;
  int q2 = (qcnt[2] + TQ - 1) >> 4, q3 = (qcnt[3] + TQ - 1) >> 4;
  int nt0 = q0 * s0, nt1 = q1 * s1, nt2 = q2 * s2, nt3 = q3 * s3;
  unsigned total = (unsigned)(nt0 + nt1 + nt2 + nt3);

  int t = threadIdx.x;
  int lane = t & 63, wid = t >> 6;
  __shared__ unsigned long long red[4][TQ];
  __shared__ unsigned sTicket;

  for (;;) {
    if (t == 0) sTicket = atomicAdd(wcnt, 1u);
    __syncthreads();
    unsigned w = sTicket;
    if (w >= total) break;
    int b, sl, qtile, kc;
    decode_id(w, nt0, nt1, nt2, q0, q1, q2, q3, k0c, k1c, k2c, k3c, b, sl, qtile, kc);
    run_item(qpack, kpack, partials, red, b, sl, qtile, kc, t, lane, wid);
    // run_item ends with __syncthreads(): safe to overwrite sTicket next iter
  }
}

// --- K4: reduce slices -> srcmap --------------------------------------------
__global__ void argmax_pass2(const unsigned long long* __restrict__ partials,
                             const int* __restrict__ qcnt, const int* __restrict__ kcnt,
                             const int* __restrict__ qlist, const int* __restrict__ klist,
                             int* __restrict__ srcmap) {
  int idx = blockIdx.x * 256 + threadIdx.x;  // [0, 16384)
  int b = idx >> 12, qpos = idx & (HW - 1);
  if (qpos >= qcnt[b]) return;
  int kc = kcnt[b];
  int ns = (kc + SLK - 1) >> 9;
  int qtile = qpos >> 4, q = qpos & (TQ - 1);
  unsigned long long v = 0ull;
  for (int s = 0; s < ns; ++s) {
    unsigned long long p = partials[(((size_t)b * NSL_MAX + s) * QT16_MAX + qtile) * TQ + q];
    if (p > v) v = p;
  }
  if (!v) return;
  int kk = (int)(0xFFFFFFFFu - (unsigned)(v & 0xFFFFFFFFull));
  srcmap[b * HW + qlist[b * HW + qpos]] = klist[b * HW + kk];
}

// --- K5: all outputs: passthrough copy (float4) + shifted gather -------------
__global__ void out_kernel(const float* __restrict__ in, const int* __restrict__ srcmap,
                           float* __restrict__ out) {
  int bid = blockIdx.x;
  if (bid < 8192) {
    size_t idx = (size_t)bid * 256 + threadIdx.x;
    int b = (int)(idx >> 19);
    size_t r = idx & 524287;
    float4 v = ((const float4*)in)[((size_t)b << 19) + r];
    ((float4*)(out + (size_t)b * 768 * HW))[r] = v;
  } else {
    int idx = (bid - 8192) * 256 + threadIdx.x;   // [0, 2^22)
    int j = idx & (HW - 1);
    int c = (idx >> 12) & 255;
    int b = idx >> 20;
    int s = srcmap[b * HW + j];
    float v = (s >= 0) ? in[((size_t)b * 512 + c) * HW + s] : 0.f;
    out[((size_t)b * 768 + 512 + c) * HW + j] = v;
  }
}

extern "C" void kernel_launch(void* const* d_in, const int* in_sizes, int n_in,
                              void* d_out, int out_size, void* d_ws, size_t ws_size,
                              hipStream_t stream) {
  const float* in = (const float*)d_in[0];
  const int* mask = (const int*)d_in[1];
  float* out = (float*)d_out;

  // workspace layout (~35 MB)
  unsigned long long* partials = (unsigned long long*)d_ws;                    // 4*8*256*16 u64 = 1 MB
  float* kpack = (float*)(partials + (size_t)BZd * NSL_MAX * QT16_MAX * TQ);   // 16.8 MB
  float* qpack = kpack + (size_t)BZd * C2 * HW;                                 // 16.8 MB
  float* inv = qpack + (size_t)BZd * C2 * HW;                                   // 64 KB
  int* qlist = (int*)(inv + BZd * HW);                                          // 64 KB
  int* klist = qlist + BZd * HW;                                                // 64 KB
  int* srcmap = klist + BZd * HW;                                               // 64 KB
  int* qcnt = srcmap + BZd * HW;                                                // 16 B
  int* kcnt = qcnt + BZd;                                                       // 16 B
  unsigned* wcnt = (unsigned*)(kcnt + BZd);                                     // 4 B

  hipLaunchKernelGGL(prep_kernel, dim3(64 + BZd), dim3(256), 0, stream,
                     in, mask, inv, qcnt, kcnt, qlist, klist, srcmap, wcnt);
  hipLaunchKernelGGL(pack_kernel, dim3(8, C2, BZd), dim3(256), 0, stream,
                     in, inv, qcnt, kcnt, qlist, klist, kpack, qpack);
  hipLaunchKernelGGL(argmax_pass1, dim3(P1_GRID), dim3(BT), 0, stream,
                     qpack, kpack, qcnt, kcnt, partials, wcnt);
  hipLaunchKernelGGL(argmax_pass2, dim3(BZd * HW / 256), dim3(256), 0, stream,
                     partials, qcnt, kcnt, qlist, klist, srcmap);
  hipLaunchKernelGGL(out_kernel, dim3(8192 + 16384), dim3(256), 0, stream,
                     in, srcmap, out);
}

// Round 6
// 228.102 us; speedup vs baseline: 1.3604x; 1.3604x over previous
//
#include <hip/hip_runtime.h>

// InnerShiftTriple: bz=4, c=512 (c2=256), h=w=64 (hw=4096), fp32 in/out, int32 mask.
// out = concat([former, latter, shifted]); shifted[i] = former[argmax_j sim(i,j)]
// for masked i over non-masked keys j, cosine sim of "latter" features.
// Argmax invariant to query normalization -> only keys normalized.
//
// Pass1 (R4 config, known-good 125us): TQ=32 x 512-key items, static schedule
// with quarter-remainder round; queries SGPR-broadcast; float2 key stream.
// R5 lesson: TQ=16 + work-steal REGRESSED (177us) -- same VALU cycles, but
// halving FMA per c-iter doubled exposed load latency (64cyc issue vs ~300cyc
// latency). Latency-bound, not schedule-bound: reverted.
// THIS ROUND: aux kernels were 142us of 267 (floor ~35us). All scattered 4B
// global gathers (pack: lat[j]/dn[j]; out: in[...,s(j)] line-per-element) are
// restaged through LDS rows with coalesced float4 global traffic; prep norm
// gets 4x parallelism (256 blocks, c-group partial sums + LDS reduce).

#define HW 4096
#define C2 256
#define BZd 4
#define TQ 32         // queries per full work item (SGPR-broadcast)
#define NK 2          // keys per thread (one float2)
#define BT 256        // pass1 block = 4 waves; block covers BT*NK = 512 keys
#define SLK 512       // keys per slice
#define NSL_MAX 8     // up to 8 slices of 512 keys
#define QT_MAX 128    // HW/TQ
#define P1_GRID 1024  // exactly the resident capacity at 4 blocks/CU

__device__ __forceinline__ unsigned ordf(float f) {
  unsigned u = __float_as_uint(f);
  return (u & 0x80000000u) ? ~u : (u | 0x80000000u);
}

__device__ __forceinline__ unsigned long long shfl_down_u64(unsigned long long v, int off) {
  unsigned lo = (unsigned)v, hi = (unsigned)(v >> 32);
  lo = __shfl_down(lo, off, 64);
  hi = __shfl_down(hi, off, 64);
  return ((unsigned long long)hi << 32) | lo;
}

// --- K1: inv-norm (blocks 0..255, 4x parallel over c-groups) + mask
//         compaction (blocks 256..259) ---------------------------------------
__global__ void prep_kernel(const float* __restrict__ in, const int* __restrict__ mask,
                            float* __restrict__ inv, int* __restrict__ qcnt,
                            int* __restrict__ kcnt, int* __restrict__ qlist,
                            int* __restrict__ klist, int* __restrict__ srcmap) {
  int bid = blockIdx.x, t = threadIdx.x;
  if (bid < 256) {
    // 64 pixels per block x 4 c-groups of 64 channels
    __shared__ float sred[4][64];
    int p = t & 63, g = t >> 6;
    int idx = bid * 64 + p;                   // [0, 16384); 64 | HW so no b-crossing
    int b = idx >> 12, j = idx & (HW - 1);
    const float* base = in + ((size_t)b * 512 + C2 + g * 64) * HW + j;
    float ss = 0.f;
#pragma unroll 8
    for (int c = 0; c < 64; ++c) { float v = base[(size_t)c * HW]; ss = fmaf(v, v, ss); }
    sred[g][p] = ss;
    __syncthreads();
    if (g == 0) {
      float s0 = ((sred[0][p] + sred[1][p]) + sred[2][p]) + sred[3][p];
      inv[idx] = 1.0f / (sqrtf(s0) + 1e-8f);
    }
  } else {
    int b = bid - 256;
    __shared__ int s[256];
    const int* m = mask + b * HW;
    int base = t * 16;
    int fl = 0, cq = 0;
#pragma unroll
    for (int i = 0; i < 16; ++i) { int f = (m[base + i] >= 1); fl |= f << i; cq += f; }
    s[t] = cq; __syncthreads();
    for (int off = 1; off < 256; off <<= 1) {
      int v = (t >= off) ? s[t - off] : 0;
      __syncthreads(); s[t] += v; __syncthreads();
    }
    int total = s[255];
    int qp = s[t] - cq;
    int kp = base - qp;
    for (int i = 0; i < 16; ++i) {
      int j = base + i;
      if ((fl >> i) & 1) qlist[b * HW + qp++] = j;
      else               klist[b * HW + kp++] = j;
      srcmap[b * HW + j] = -1;
    }
    if (t == 0) { qcnt[b] = total; kcnt[b] = HW - total; }
  }
}

// --- K2: pack normalized keys + un-normalized queries via LDS-staged gather.
// One block per (b,c): stage lat row + inv row in LDS (coalesced float4 reads),
// gather from LDS, write kpack/qpack rows coalesced. Same lat[j]*dn[j] product
// as before -> kpack bit-identical.
__global__ void pack_kernel(const float* __restrict__ in, const float* __restrict__ inv,
                            const int* __restrict__ qcnt, const int* __restrict__ kcnt,
                            const int* __restrict__ qlist, const int* __restrict__ klist,
                            float* __restrict__ kpack, float* __restrict__ qpack) {
  __shared__ float slat[HW];   // 16 KB
  __shared__ float sinv[HW];   // 16 KB
  int t = threadIdx.x;
  int c = blockIdx.x, b = blockIdx.y;
  const float4* lat4 = (const float4*)(in + ((size_t)b * 512 + C2 + c) * HW);
  const float4* inv4 = (const float4*)(inv + (size_t)b * HW);
#pragma unroll
  for (int i = 0; i < 4; ++i) {
    int p = i * 256 + t;
    ((float4*)slat)[p] = lat4[p];
    ((float4*)sinv)[p] = inv4[p];
  }
  int kc = kcnt[b], nq = qcnt[b];
  const int* kl = klist + b * HW;
  const int* ql = qlist + b * HW;
  float* kdst = kpack + (size_t)(b * C2 + c) * HW;
  float* qdst = qpack + (size_t)(b * C2 + c) * HW;
  __syncthreads();
#pragma unroll
  for (int i = 0; i < 4; ++i) {
    int jj = (i * 256 + t) * 4;
    int4 k4 = *(const int4*)(kl + jj);   // entries beyond kc are garbage: guarded
    int4 q4 = *(const int4*)(ql + jj);
    float4 kv, qv;
    kv.x = (jj + 0 < kc) ? slat[k4.x] * sinv[k4.x] : 0.f;
    kv.y = (jj + 1 < kc) ? slat[k4.y] * sinv[k4.y] : 0.f;
    kv.z = (jj + 2 < kc) ? slat[k4.z] * sinv[k4.z] : 0.f;
    kv.w = (jj + 3 < kc) ? slat[k4.w] * sinv[k4.w] : 0.f;
    qv.x = (jj + 0 < nq) ? slat[q4.x] : 0.f;
    qv.y = (jj + 1 < nq) ? slat[q4.y] : 0.f;
    qv.z = (jj + 2 < nq) ? slat[q4.z] : 0.f;
    qv.w = (jj + 3 < nq) ? slat[q4.w] : 0.f;
    *(float4*)(kdst + jj) = kv;
    *(float4*)(qdst + jj) = qv;
  }
}

// --- K3 helpers (R4, unchanged) ----------------------------------------------
__device__ __forceinline__ void decode_id(unsigned idx,
    int nt0, int nt1, int nt2,
    int q0, int q1, int q2, int q3,
    int k0c, int k1c, int k2c, int k3c,
    int& b, int& sl, int& qtile, int& kc) {
  int qtn;
  b = 0; qtn = q0; kc = k0c;
  if (idx >= (unsigned)nt0) {
    idx -= nt0; b = 1; qtn = q1; kc = k1c;
    if (idx >= (unsigned)nt1) {
      idx -= nt1; b = 2; qtn = q2; kc = k2c;
      if (idx >= (unsigned)nt2) { idx -= nt2; b = 3; qtn = q3; kc = k3c; }
    }
  }
  sl = (int)(idx / (unsigned)qtn);
  qtile = (int)(idx - (unsigned)sl * (unsigned)qtn);
}

// One work item: TQL queries (qtile*32 + qoff ..) x one 512-key slice.
// Per-query fmaf chain is independent of TQL -> bit-exact vs TQ=32 full item.
template <int TQL>
__device__ __forceinline__ void run_item(
    const float* __restrict__ qpack, const float* __restrict__ kpack,
    unsigned long long* __restrict__ partials,
    unsigned long long (*red)[TQ],
    int b, int sl, int qtile, int qoff, int kc,
    int t, int lane, int wid) {
  int qstart = (qtile << 5) + qoff;
  int kbase = (sl << 9) + (t << 1);   // this thread's 2 keys

  // wave-uniform query base -> scalar loads (SGPR broadcast operands)
  const float* qb = qpack + ((size_t)b * C2) * HW + qstart;
  const float* kcol = kpack + ((size_t)b * C2) * HW + kbase;

  float acc[NK][TQL];
#pragma unroll
  for (int r = 0; r < NK; ++r)
#pragma unroll
    for (int q = 0; q < TQL; ++q) acc[r][q] = 0.f;

  // rotating depth-2 prefetch of the key float2 (stride HW floats per c)
  float2 k0 = *(const float2*)(kcol);
  float2 k1 = *(const float2*)(kcol + HW);
#pragma unroll 2
  for (int c = 0; c < C2; ++c) {
    float2 kq = k0;
    k0 = k1;
    int cp = c + 2; if (cp > C2 - 1) cp = C2 - 1;
    k1 = *(const float2*)(kcol + (size_t)cp * HW);
    float kv[NK] = {kq.x, kq.y};
    const float* qc_ = qb + (size_t)c * HW;   // uniform address
#pragma unroll
    for (int i = 0; i < TQL; ++i) {
      float qv = qc_[i];                       // s_load -> SGPR
#pragma unroll
      for (int r = 0; r < NK; ++r)
        acc[r][i] = fmaf(kv[r], qv, acc[r][i]);
    }
  }

  // per-q reduction: wave shfl, then cross-wave via LDS
#pragma unroll
  for (int q = 0; q < TQL; ++q) {
    unsigned long long v = 0ull;
#pragma unroll
    for (int r = 0; r < NK; ++r) {
      int kk = kbase + r;
      if (kk < kc) {
        unsigned long long pk =
            ((unsigned long long)ordf(acc[r][q]) << 32) | (unsigned)(0xFFFFFFFFu - (unsigned)kk);
        if (pk > v) v = pk;
      }
    }
#pragma unroll
    for (int off = 32; off >= 1; off >>= 1) {
      unsigned long long o = shfl_down_u64(v, off);
      if (o > v) v = o;
    }
    if (lane == 0) red[wid][q] = v;
  }
  __syncthreads();
  if (t < TQL) {
    unsigned long long v = red[0][t];
#pragma unroll
    for (int ww = 1; ww < 4; ++ww) if (red[ww][t] > v) v = red[ww][t];
    partials[(((size_t)b * NSL_MAX + sl) * QT_MAX + qtile) * TQ + qoff + t] = v;
  }
  __syncthreads();
}

// --- K3: fused GEMM + per-slice argmax over dense (b,sl,qtile) work items ----
// F = N/S full rounds of 32q x 512k items; remainder R items run as 4R
// quarter items (8q x 512k) so the last round costs 0.25T instead of T.
__global__ __launch_bounds__(BT, 4) void argmax_pass1(
    const float* __restrict__ qpack, const float* __restrict__ kpack,
    const int* __restrict__ qcnt, const int* __restrict__ kcnt,
    unsigned long long* __restrict__ partials) {
  // per-batch work-item counts (uniform -> scalar)
  int k0c = kcnt[0], k1c = kcnt[1], k2c = kcnt[2], k3c = kcnt[3];
  int s0 = (k0c + SLK - 1) >> 9, s1 = (k1c + SLK - 1) >> 9;
  int s2 = (k2c + SLK - 1) >> 9, s3 = (k3c + SLK - 1) >> 9;
  int q0 = (qcnt[0] + TQ - 1) >> 5, q1 = (qcnt[1] + TQ - 1) >> 5;
  int q2 = (qcnt[2] + TQ - 1) >> 5, q3 = (qcnt[3] + TQ - 1) >> 5;
  int nt0 = q0 * s0, nt1 = q1 * s1, nt2 = q2 * s2, nt3 = q3 * s3;
  unsigned total = (unsigned)(nt0 + nt1 + nt2 + nt3);
  unsigned S = gridDim.x;
  unsigned F = total / S;
  unsigned fullN = F * S;
  unsigned R = total - fullN;

  int t = threadIdx.x;
  int lane = t & 63, wid = t >> 6;
  __shared__ unsigned long long red[4][TQ];

  // phase 1: full-size items (all S slots busy for F rounds)
  for (unsigned w = blockIdx.x; w < fullN; w += S) {
    int b, sl, qtile, kc;
    decode_id(w, nt0, nt1, nt2, q0, q1, q2, q3, k0c, k1c, k2c, k3c, b, sl, qtile, kc);
    run_item<TQ>(qpack, kpack, partials, red, b, sl, qtile, 0, kc, t, lane, wid);
  }
  // phase 2: remainder items split 4-ways along q (quarter-duration round)
  for (unsigned qi = blockIdx.x; qi < 4u * R; qi += S) {
    unsigned id = fullN + (qi >> 2);
    int sub = (int)(qi & 3u);
    int b, sl, qtile, kc;
    decode_id(id, nt0, nt1, nt2, q0, q1, q2, q3, k0c, k1c, k2c, k3c, b, sl, qtile, kc);
    run_item<8>(qpack, kpack, partials, red, b, sl, qtile, sub * 8, kc, t, lane, wid);
  }
}

// --- K4: reduce slices -> srcmap --------------------------------------------
__global__ void argmax_pass2(const unsigned long long* __restrict__ partials,
                             const int* __restrict__ qcnt, const int* __restrict__ kcnt,
                             const int* __restrict__ qlist, const int* __restrict__ klist,
                             int* __restrict__ srcmap) {
  int idx = blockIdx.x * 256 + threadIdx.x;  // [0, 16384)
  int b = idx >> 12, qpos = idx & (HW - 1);
  if (qpos >= qcnt[b]) return;
  int kc = kcnt[b];
  int ns = (kc + SLK - 1) >> 9;
  int qtile = qpos >> 5, q = qpos & (TQ - 1);
  unsigned long long v = 0ull;
  for (int s = 0; s < ns; ++s) {
    unsigned long long p = partials[(((size_t)b * NSL_MAX + s) * QT_MAX + qtile) * TQ + q];
    if (p > v) v = p;
  }
  if (!v) return;
  int kk = (int)(0xFFFFFFFFu - (unsigned)(v & 0xFFFFFFFFull));
  srcmap[b * HW + qlist[b * HW + qpos]] = klist[b * HW + kk];
}

// --- K5: one block per (b,c) plane: coalesced row load -> LDS; passthrough
// write; for c<256 the same LDS row serves the shifted gather (lds[s]) --------
__global__ void out_kernel(const float* __restrict__ in, const int* __restrict__ srcmap,
                           float* __restrict__ out) {
  __shared__ float srow[HW];   // 16 KB
  int bid = blockIdx.x;
  int b = bid >> 9, c = bid & 511;
  int t = threadIdx.x;
  const float4* src = (const float4*)(in + ((size_t)b * 512 + c) * HW);
  float4* dst = (float4*)(out + ((size_t)b * 768 + c) * HW);
#pragma unroll
  for (int i = 0; i < 4; ++i) {
    int p = i * 256 + t;
    float4 v = src[p];
    ((float4*)srow)[p] = v;
    dst[p] = v;
  }
  if (c < 256) {
    __syncthreads();
    const int* sm = srcmap + b * HW;
    float4* dst2 = (float4*)(out + ((size_t)b * 768 + 512 + c) * HW);
#pragma unroll
    for (int i = 0; i < 4; ++i) {
      int p = i * 256 + t;
      int j0 = p * 4;
      int4 s4 = *(const int4*)(sm + j0);
      float4 o;
      o.x = (s4.x >= 0) ? srow[s4.x] : 0.f;
      o.y = (s4.y >= 0) ? srow[s4.y] : 0.f;
      o.z = (s4.z >= 0) ? srow[s4.z] : 0.f;
      o.w = (s4.w >= 0) ? srow[s4.w] : 0.f;
      dst2[p] = o;
    }
  }
}

extern "C" void kernel_launch(void* const* d_in, const int* in_sizes, int n_in,
                              void* d_out, int out_size, void* d_ws, size_t ws_size,
                              hipStream_t stream) {
  const float* in = (const float*)d_in[0];
  const int* mask = (const int*)d_in[1];
  float* out = (float*)d_out;

  // workspace layout (~35 MB)
  unsigned long long* partials = (unsigned long long*)d_ws;                    // 4*8*128*32 u64 = 1 MB
  float* kpack = (float*)(partials + (size_t)BZd * NSL_MAX * QT_MAX * TQ);     // 16.8 MB
  float* qpack = kpack + (size_t)BZd * C2 * HW;                                 // 16.8 MB
  float* inv = qpack + (size_t)BZd * C2 * HW;                                   // 64 KB
  int* qlist = (int*)(inv + BZd * HW);                                          // 64 KB
  int* klist = qlist + BZd * HW;                                                // 64 KB
  int* srcmap = klist + BZd * HW;                                               // 64 KB
  int* qcnt = srcmap + BZd * HW;                                                // 16 B
  int* kcnt = qcnt + BZd;                                                       // 16 B

  hipLaunchKernelGGL(prep_kernel, dim3(256 + BZd), dim3(256), 0, stream,
                     in, mask, inv, qcnt, kcnt, qlist, klist, srcmap);
  hipLaunchKernelGGL(pack_kernel, dim3(C2, BZd), dim3(256), 0, stream,
                     in, inv, qcnt, kcnt, qlist, klist, kpack, qpack);
  hipLaunchKernelGGL(argmax_pass1, dim3(P1_GRID), dim3(BT), 0, stream,
                     qpack, kpack, qcnt, kcnt, partials);
  hipLaunchKernelGGL(argmax_pass2, dim3(BZd * HW / 256), dim3(256), 0, stream,
                     partials, qcnt, kcnt, qlist, klist, srcmap);
  hipLaunchKernelGGL(out_kernel, dim3(BZd * 512), dim3(256), 0, stream,
                     in, srcmap, out);
}